// Round 6
// baseline (594.058 us; speedup 1.0000x reference)
//
#include <hip/hip_runtime.h>
#include <math.h>

#define NLVL 16
#define MAX_ENTRY (1 << 19)
#define NPTS (1 << 20)

typedef float f2_t __attribute__((ext_vector_type(2)));
typedef float f4_t __attribute__((ext_vector_type(4)));

__device__ __forceinline__ void nt_store2(float2 v, float2* p) {
    f2_t t; t.x = v.x; t.y = v.y;
    __builtin_nontemporal_store(t, (f2_t*)p);
}
__device__ __forceinline__ void nt_store4(float4 v, float4* p) {
    f4_t t; t.x = v.x; t.y = v.y; t.z = v.z; t.w = v.w;
    __builtin_nontemporal_store(t, (f4_t*)p);
}
__device__ __forceinline__ float2 nt_load2(const float2* p) {
    f2_t t = __builtin_nontemporal_load((const f2_t*)p);
    return make_float2(t.x, t.y);
}
__device__ __forceinline__ float4 nt_load4(const float4* p) {
    f4_t t = __builtin_nontemporal_load((const f4_t*)p);
    return make_float4(t.x, t.y, t.z, t.w);
}

// OFFSETS table from the reference (NOT binary order); weights in binary order.
__device__ __constant__ int OX[8] = {0, 0, 0, 0, 1, 1, 1, 1};
__device__ __constant__ int OY[8] = {0, 1, 0, 1, 0, 0, 1, 1};
__device__ __constant__ int OZ[8] = {0, 0, 1, 1, 0, 1, 0, 1};

__device__ __forceinline__ void corner_setup(
    float x0, float x1, float x2, float s, float hi,
    int& cx, int& cy, int& cz,
    float (&wx)[2], float (&wy)[2], float (&wz)[2])
{
    float c0 = fminf(fmaxf(x0 * s, 0.0f), hi);
    float c1 = fminf(fmaxf(x1 * s, 0.0f), hi);
    float c2 = fminf(fmaxf(x2 * s, 0.0f), hi);
    float f0 = floorf(c0), f1 = floorf(c1), f2 = floorf(c2);
    cx = (int)f0; cy = (int)f1; cz = (int)f2;
    float xx = c0 - f0, yy = c1 - f1, zz = c2 - f2;
    wx[0] = 1.0f - xx; wx[1] = xx;
    wy[0] = 1.0f - yy; wy[1] = yy;
    wz[0] = 1.0f - zz; wz[1] = zz;
}

__device__ __forceinline__ void load_xyz(
    const float* __restrict__ x, const float4* __restrict__ xp, int i,
    float& x0, float& x1, float& x2)
{
    if (xp) {
        const float4 v = nt_load4(&xp[i]);
        x0 = v.x; x1 = v.y; x2 = v.z;
    } else {
        x0 = __builtin_nontemporal_load(&x[3 * i + 0]);
        x1 = __builtin_nontemporal_load(&x[3 * i + 1]);
        x2 = __builtin_nontemporal_load(&x[3 * i + 2]);
    }
}

// ======================= optimized path =======================

struct DenseP {
    int res[6];
    int res2[6];
    float scale[6];
    float hi[6];
    long long packoff[4];   // float4-index offsets, levels 1..3
    long long nent[6];      // res^3
};

// Pack dense levels 1..3 into x-paired float4; optionally pack x into float4.
__global__ __launch_bounds__(256) void repack_kernel(
    const float* __restrict__ x,
    const float* __restrict__ tables,
    float4* __restrict__ pack,
    float4* __restrict__ xp,
    DenseP P)
{
    const long long stride = (long long)gridDim.x * 256;
    const long long tid = (long long)blockIdx.x * 256 + threadIdx.x;
    for (int l = 1; l <= 3; ++l) {
        const float2* tab = (const float2*)(tables + (size_t)l * MAX_ENTRY * 2);
        float4* dst = pack + P.packoff[l];
        const long long n = P.nent[l];
        for (long long k = tid; k < n; k += stride) {
            const float2 a = tab[k];
            const float2 b = tab[k + 1];   // within the level's MAX_ENTRY row
            nt_store4(make_float4(a.x, a.y, b.x, b.y), &dst[k]);
        }
    }
    if (xp) {
        for (long long i = tid; i < NPTS; i += stride) {
            xp[i] = make_float4(x[3 * i + 0], x[3 * i + 1], x[3 * i + 2], 0.0f);
        }
    }
}

// Dense levels 0..4. L0 in LDS; L1..3 packed float4; L4 adjacent-pair float2.
__global__ __launch_bounds__(256) void dense_kernel(
    const float* __restrict__ x,
    const float4* __restrict__ xp,
    const float* __restrict__ tables,
    const float4* __restrict__ pack,
    float2* __restrict__ feat,
    DenseP P)
{
    __shared__ float2 lds0[4096];
    {
        const float2* tab0 = (const float2*)tables;
        for (int j = threadIdx.x; j < 4096; j += 256) lds0[j] = tab0[j];
    }
    __syncthreads();

    const int i = blockIdx.x * 256 + threadIdx.x;
    if (i >= NPTS) return;

    float x0, x1, x2;
    load_xyz(x, xp, i, x0, x1, x2);

    // ---- level 0 from LDS ----
    {
        int cx, cy, cz;
        float wx[2], wy[2], wz[2];
        corner_setup(x0, x1, x2, P.scale[0], P.hi[0], cx, cy, cz, wx, wy, wz);
        const int res = P.res[0], res2 = P.res2[0];
        const int base = cx + cy * res + cz * res2;
        float a0 = 0.0f, a1 = 0.0f;
#pragma unroll
        for (int k = 0; k < 8; ++k) {
            const int idx = base + OX[k] + OY[k] * res + OZ[k] * res2;
            const float2 f = lds0[idx];
            const float w = wx[k & 1] * wy[(k >> 1) & 1] * wz[k >> 2];
            a0 += w * f.x; a1 += w * f.y;
        }
        nt_store2(make_float2(a0, a1), &feat[i]);
    }

    // ---- levels 1..3 from packed float4 ----
#pragma unroll
    for (int l = 1; l <= 3; ++l) {
        int cx, cy, cz;
        float wx[2], wy[2], wz[2];
        corner_setup(x0, x1, x2, P.scale[l], P.hi[l], cx, cy, cz, wx, wy, wz);
        const int res = P.res[l], res2 = P.res2[l];
        const int base = cx + cy * res + cz * res2;
        const float4* pk = pack + P.packoff[l];

        float a0 = 0.0f, a1 = 0.0f;
#pragma unroll
        for (int j = 0; j < 4; ++j) {
            const int idx = base + (j & 1) * res + (j >> 1) * res2;
            const float4 f = pk[idx];
            const float w0 = wx[j & 1] * wy[j >> 1] * wz[0];
            const float w1 = wx[j >> 1] * wy[j & 1] * wz[1];
            a0 += w0 * f.x + w1 * f.z;
            a1 += w0 * f.y + w1 * f.w;
        }
        nt_store2(make_float2(a0, a1), &feat[(size_t)l * NPTS + i]);
    }

    // ---- level 4 unpacked, adjacent-pair float2 ----
    {
        const int l = 4;
        int cx, cy, cz;
        float wx[2], wy[2], wz[2];
        corner_setup(x0, x1, x2, P.scale[l], P.hi[l], cx, cy, cz, wx, wy, wz);
        const int res = P.res[l], res2 = P.res2[l];
        const int base = cx + cy * res + cz * res2;
        const float2* tab = (const float2*)tables + (size_t)l * MAX_ENTRY;

        float a0 = 0.0f, a1 = 0.0f;
#pragma unroll
        for (int j = 0; j < 4; ++j) {
            const int idx = base + (j & 1) * res + (j >> 1) * res2;
            const float2 flo = tab[idx];
            const float2 fhi = tab[idx + 1];
            const float w0 = wx[j & 1] * wy[j >> 1] * wz[0];
            const float w1 = wx[j >> 1] * wy[j & 1] * wz[1];
            a0 += w0 * flo.x + w1 * fhi.x;
            a1 += w0 * flo.y + w1 * fhi.y;
        }
        nt_store2(make_float2(a0, a1), &feat[(size_t)l * NPTS + i]);
    }
}

// Level 5 (res=80, 4.1 MB table ~ L2): own pass, adjacent-pair float2, 2 pts/thread.
__global__ __launch_bounds__(256) void dense5_kernel(
    const float* __restrict__ x,
    const float4* __restrict__ xp,
    const float2* __restrict__ tab,
    float2* __restrict__ featl,
    int res, int res2, float scale, float hi)
{
    const int t = blockIdx.x * 256 + threadIdx.x;
#pragma unroll
    for (int h = 0; h < 2; ++h) {
        const int i = t + h * (NPTS / 2);
        float x0, x1, x2;
        load_xyz(x, xp, i, x0, x1, x2);

        int cx, cy, cz;
        float wx[2], wy[2], wz[2];
        corner_setup(x0, x1, x2, scale, hi, cx, cy, cz, wx, wy, wz);
        const int base = cx + cy * res + cz * res2;

        float a0 = 0.0f, a1 = 0.0f;
#pragma unroll
        for (int j = 0; j < 4; ++j) {
            const int idx = base + (j & 1) * res + (j >> 1) * res2;
            const float2 flo = tab[idx];
            const float2 fhi = tab[idx + 1];
            const float w0 = wx[j & 1] * wy[j >> 1] * wz[0];
            const float w1 = wx[j >> 1] * wy[j & 1] * wz[1];
            a0 += w0 * flo.x + w1 * fhi.x;
            a1 += w0 * flo.y + w1 * fhi.y;
        }
        nt_store2(make_float2(a0, a1), &featl[i]);
    }
}

// One hashed level per launch; 4 points/thread; all 32 gathers issued before
// any accumulation (MLP experiment). All arrays fully unrolled / static-indexed.
__global__ __launch_bounds__(256) void hash_kernel(
    const float* __restrict__ x,
    const float4* __restrict__ xp,
    const float2* __restrict__ tab,
    float2* __restrict__ featl,
    float scale, float hi)
{
    const int t = blockIdx.x * 256 + threadIdx.x;   // 0 .. NPTS/4-1
    const unsigned P0 = 3367900313u, P1 = 2654435761u, P2 = 805459861u;

    unsigned hx[4][2], hy[4][2], hz[4][2];
    float wx[4][2], wy[4][2], wz[4][2];

#pragma unroll
    for (int h = 0; h < 4; ++h) {
        const int i = t + h * (NPTS / 4);
        float x0, x1, x2;
        load_xyz(x, xp, i, x0, x1, x2);
        int cx, cy, cz;
        corner_setup(x0, x1, x2, scale, hi, cx, cy, cz, wx[h], wy[h], wz[h]);
        hx[h][0] = (unsigned)cx * P0; hx[h][1] = hx[h][0] + P0;
        hy[h][0] = (unsigned)cy * P1; hy[h][1] = hy[h][0] + P1;
        hz[h][0] = (unsigned)cz * P2; hz[h][1] = hz[h][0] + P2;
    }

    // Issue all 32 gathers back-to-back.
    float2 f[4][8];
#pragma unroll
    for (int h = 0; h < 4; ++h) {
#pragma unroll
        for (int k = 0; k < 8; ++k) {
            const unsigned idx =
                (hx[h][OX[k]] ^ hy[h][OY[k]] ^ hz[h][OZ[k]]) & (MAX_ENTRY - 1);
            f[h][k] = tab[idx];
        }
    }

    // Accumulate and store.
#pragma unroll
    for (int h = 0; h < 4; ++h) {
        float a0 = 0.0f, a1 = 0.0f;
#pragma unroll
        for (int k = 0; k < 8; ++k) {
            const float w = wx[h][k & 1] * wy[h][(k >> 1) & 1] * wz[h][k >> 2];
            a0 += w * f[h][k].x;
            a1 += w * f[h][k].y;
        }
        const int i = t + h * (NPTS / 4);
        nt_store2(make_float2(a0, a1), &featl[i]);
    }
}

// feat[16][NPTS] (float2) -> out[NPTS][32] floats, coalesced float4 writes.
__global__ __launch_bounds__(256) void assemble_kernel(
    const float2* __restrict__ feat, float4* __restrict__ out)
{
    const size_t tid = (size_t)blockIdx.x * 256 + threadIdx.x;  // 0 .. 8M-1
    const int    c   = (int)(tid & 7);
    const size_t p   = tid >> 3;
    const float2 a = nt_load2(&feat[(size_t)(2 * c) * NPTS + p]);
    const float2 b = nt_load2(&feat[(size_t)(2 * c + 1) * NPTS + p]);
    nt_store4(make_float4(a.x, a.y, b.x, b.y), &out[tid]);
}

// ======================= fallback path (round-2, known-good) =======================

struct DenseParams {
    int   res[6];
    int   res2[6];
    float scale[6];
    float hi[6];
    long long tab_off[6];
};

__device__ __forceinline__ float2 hash_point_fb(
    float x0, float x1, float x2, const float2* __restrict__ tab,
    float scale, float hi)
{
    int cx, cy, cz;
    float wx[2], wy[2], wz[2];
    corner_setup(x0, x1, x2, scale, hi, cx, cy, cz, wx, wy, wz);
    const unsigned P0 = 3367900313u, P1 = 2654435761u, P2 = 805459861u;
    unsigned hx[2], hy[2], hz[2];
    hx[0] = (unsigned)cx * P0; hx[1] = hx[0] + P0;
    hy[0] = (unsigned)cy * P1; hy[1] = hy[0] + P1;
    hz[0] = (unsigned)cz * P2; hz[1] = hz[0] + P2;
    float a0 = 0.0f, a1 = 0.0f;
#pragma unroll
    for (int k = 0; k < 8; ++k) {
        const unsigned idx = (hx[OX[k]] ^ hy[OY[k]] ^ hz[OZ[k]]) & (MAX_ENTRY - 1);
        const float2 f = tab[idx];
        const float w = wx[k & 1] * wy[(k >> 1) & 1] * wz[k >> 2];
        a0 += w * f.x; a1 += w * f.y;
    }
    return make_float2(a0, a1);
}

__global__ __launch_bounds__(256) void dense6_kernel(
    const float* __restrict__ x,
    const float* __restrict__ tables,
    float* __restrict__ out,
    DenseParams P)
{
    const int i = blockIdx.x * 256 + threadIdx.x;
    if (i >= NPTS) return;
    const float x0 = x[3 * i + 0];
    const float x1 = x[3 * i + 1];
    const float x2 = x[3 * i + 2];
    float o[12];
#pragma unroll
    for (int l = 0; l < 6; ++l) {
        int cx, cy, cz;
        float wx[2], wy[2], wz[2];
        corner_setup(x0, x1, x2, P.scale[l], P.hi[l], cx, cy, cz, wx, wy, wz);
        const float2* tab = (const float2*)(tables + P.tab_off[l]);
        const int res  = P.res[l];
        const int res2 = P.res2[l];
        const int base = cx + cy * res + cz * res2;
        float a0 = 0.0f, a1 = 0.0f;
#pragma unroll
        for (int k = 0; k < 8; ++k) {
            const int idx = base + OX[k] + OY[k] * res + OZ[k] * res2;
            const float2 f = tab[idx];
            const float w = wx[k & 1] * wy[(k >> 1) & 1] * wz[k >> 2];
            a0 += w * f.x; a1 += w * f.y;
        }
        o[2 * l + 0] = a0; o[2 * l + 1] = a1;
    }
    float4* op = (float4*)(out + (size_t)i * 32);
    op[0] = ((float4*)o)[0];
    op[1] = ((float4*)o)[1];
    op[2] = ((float4*)o)[2];
}

__global__ __launch_bounds__(256) void hash_level_kernel(
    const float* __restrict__ x,
    const float* __restrict__ tables,
    float* __restrict__ out,
    int level, float scale, float hi)
{
    const int i = blockIdx.x * 256 + threadIdx.x;
    if (i >= NPTS) return;
    const float2* tab = (const float2*)tables + (size_t)level * MAX_ENTRY;
    const float2 r = hash_point_fb(x[3 * i], x[3 * i + 1], x[3 * i + 2], tab, scale, hi);
    *(float2*)(out + (size_t)i * 32 + 2 * level) = r;
}

__global__ __launch_bounds__(256) void generic_level_kernel(
    const float* __restrict__ x,
    const float* __restrict__ tables,
    float* __restrict__ out,
    int level, int res, int res2, int use_hash, float scale, float hi)
{
    const int i = blockIdx.x * 256 + threadIdx.x;
    if (i >= NPTS) return;
    const float x0 = x[3 * i + 0];
    const float x1 = x[3 * i + 1];
    const float x2 = x[3 * i + 2];
    int cx, cy, cz;
    float wx[2], wy[2], wz[2];
    corner_setup(x0, x1, x2, scale, hi, cx, cy, cz, wx, wy, wz);
    const float2* tab = (const float2*)tables + (size_t)level * MAX_ENTRY;
    float a0 = 0.0f, a1 = 0.0f;
    if (use_hash) {
        const unsigned P0 = 3367900313u, P1 = 2654435761u, P2 = 805459861u;
        unsigned hx[2], hy[2], hz[2];
        hx[0] = (unsigned)cx * P0; hx[1] = hx[0] + P0;
        hy[0] = (unsigned)cy * P1; hy[1] = hy[0] + P1;
        hz[0] = (unsigned)cz * P2; hz[1] = hz[0] + P2;
#pragma unroll
        for (int k = 0; k < 8; ++k) {
            const unsigned idx = (hx[OX[k]] ^ hy[OY[k]] ^ hz[OZ[k]]) & (MAX_ENTRY - 1);
            const float2 f = tab[idx];
            const float w = wx[k & 1] * wy[(k >> 1) & 1] * wz[k >> 2];
            a0 += w * f.x; a1 += w * f.y;
        }
    } else {
        const int base = cx + cy * res + cz * res2;
#pragma unroll
        for (int k = 0; k < 8; ++k) {
            const int idx = base + OX[k] + OY[k] * res + OZ[k] * res2;
            const float2 f = tab[idx];
            const float w = wx[k & 1] * wy[(k >> 1) & 1] * wz[k >> 2];
            a0 += w * f.x; a1 += w * f.y;
        }
    }
    *(float2*)(out + (size_t)i * 32 + 2 * level) = make_float2(a0, a1);
}

// ======================= launch =======================

extern "C" void kernel_launch(void* const* d_in, const int* in_sizes, int n_in,
                              void* d_out, int out_size, void* d_ws, size_t ws_size,
                              hipStream_t stream)
{
    const float* x      = (const float*)d_in[0];
    const float* tables = (const float*)d_in[1];
    float* out          = (float*)d_out;

    // Reproduce numpy's resolution computation bit-for-bit (same libm).
    int   res[NLVL], res2[NLVL], use_hash[NLVL];
    float scale[NLVL], hi[NLVL];
    const double b = exp((log(2048.0) - log(16.0)) / 15.0);
    for (int l = 0; l < NLVL; ++l) {
        const int r = (int)floor(16.0 * pow(b, (double)l));
        res[l]  = r;
        res2[l] = r * r;
        const long long t3 = (long long)r * r * r;
        use_hash[l] = (t3 >= (long long)MAX_ENTRY) ? 1 : 0;
        scale[l] = (float)(r - 1);
        hi[l]    = (float)((double)r - 1.0001);
    }

    const int block = 256;
    const int grid  = (NPTS + block - 1) / block;

    bool expected = true;
    for (int l = 0; l < 6; ++l)    expected = expected && !use_hash[l];
    for (int l = 6; l < NLVL; ++l) expected = expected && use_hash[l];

    // Workspace layout: pack (levels 1..3) | feat | [optional xp]
    long long packoff[4] = {0, 0, 0, 0};
    long long nent[6];
    long long packTot = 0;
    if (expected) {
        for (int l = 0; l < 6; ++l) nent[l] = (long long)res[l] * res[l] * res[l];
        for (int l = 1; l <= 3; ++l) { packoff[l] = packTot; packTot += nent[l]; }
    }
    const size_t packBytes = (size_t)packTot * 16;
    const size_t featOff   = (packBytes + 255) & ~(size_t)255;
    const size_t featBytes = (size_t)NLVL * NPTS * sizeof(float2);
    const size_t xpOff     = (featOff + featBytes + 255) & ~(size_t)255;
    const size_t need      = featOff + featBytes;
    const size_t need_xp   = xpOff + (size_t)NPTS * sizeof(float4);

    if (expected && ws_size >= need) {
        float4* pack = (float4*)d_ws;
        float2* feat = (float2*)((char*)d_ws + featOff);
        float4* xp   = (ws_size >= need_xp) ? (float4*)((char*)d_ws + xpOff) : nullptr;

        DenseP P;
        for (int l = 0; l < 6; ++l) {
            P.res[l] = res[l]; P.res2[l] = res2[l];
            P.scale[l] = scale[l]; P.hi[l] = hi[l];
            P.nent[l] = nent[l];
        }
        for (int l = 1; l <= 3; ++l) P.packoff[l] = packoff[l];
        P.packoff[0] = 0;

        repack_kernel<<<1024, block, 0, stream>>>(x, tables, pack, xp, P);
        dense_kernel<<<grid, block, 0, stream>>>(x, xp, tables, pack, feat, P);
        dense5_kernel<<<NPTS / 2 / block, block, 0, stream>>>(
            x, xp, (const float2*)tables + (size_t)5 * MAX_ENTRY,
            feat + (size_t)5 * NPTS, res[5], res2[5], scale[5], hi[5]);
        for (int l = 6; l < NLVL; ++l) {
            const float2* tab = (const float2*)tables + (size_t)l * MAX_ENTRY;
            hash_kernel<<<NPTS / 4 / block, block, 0, stream>>>(
                x, xp, tab, feat + (size_t)l * NPTS, scale[l], hi[l]);
        }
        assemble_kernel<<<(NPTS * 8) / block, block, 0, stream>>>(feat, (float4*)out);
    } else if (expected) {
        DenseParams P;
        for (int l = 0; l < 6; ++l) {
            P.res[l] = res[l]; P.res2[l] = res2[l];
            P.scale[l] = scale[l]; P.hi[l] = hi[l];
            P.tab_off[l] = (long long)l * MAX_ENTRY * 2;
        }
        dense6_kernel<<<grid, block, 0, stream>>>(x, tables, out, P);
        for (int l = 6; l < NLVL; ++l) {
            hash_level_kernel<<<grid, block, 0, stream>>>(x, tables, out, l, scale[l], hi[l]);
        }
    } else {
        for (int l = 0; l < NLVL; ++l) {
            generic_level_kernel<<<grid, block, 0, stream>>>(
                x, tables, out, l, res[l], res2[l], use_hash[l], scale[l], hi[l]);
        }
    }
}

// Round 7
// 592.174 us; speedup vs baseline: 1.0032x; 1.0032x over previous
//
#include <hip/hip_runtime.h>
#include <math.h>

#define NLVL 16
#define MAX_ENTRY (1 << 19)
#define NPTS (1 << 20)

typedef float f2_t __attribute__((ext_vector_type(2)));
typedef float f4_t __attribute__((ext_vector_type(4)));

__device__ __forceinline__ void nt_store2(float2 v, float2* p) {
    f2_t t; t.x = v.x; t.y = v.y;
    __builtin_nontemporal_store(t, (f2_t*)p);
}
__device__ __forceinline__ void nt_store4(float4 v, float4* p) {
    f4_t t; t.x = v.x; t.y = v.y; t.z = v.z; t.w = v.w;
    __builtin_nontemporal_store(t, (f4_t*)p);
}
__device__ __forceinline__ float2 nt_load2(const float2* p) {
    f2_t t = __builtin_nontemporal_load((const f2_t*)p);
    return make_float2(t.x, t.y);
}
__device__ __forceinline__ float4 nt_load4(const float4* p) {
    f4_t t = __builtin_nontemporal_load((const f4_t*)p);
    return make_float4(t.x, t.y, t.z, t.w);
}

// OFFSETS table from the reference (NOT binary order); weights in binary order.
__device__ __constant__ int OX[8] = {0, 0, 0, 0, 1, 1, 1, 1};
__device__ __constant__ int OY[8] = {0, 1, 0, 1, 0, 0, 1, 1};
__device__ __constant__ int OZ[8] = {0, 0, 1, 1, 0, 1, 0, 1};

__device__ __forceinline__ void corner_setup(
    float x0, float x1, float x2, float s, float hi,
    int& cx, int& cy, int& cz,
    float (&wx)[2], float (&wy)[2], float (&wz)[2])
{
    float c0 = fminf(fmaxf(x0 * s, 0.0f), hi);
    float c1 = fminf(fmaxf(x1 * s, 0.0f), hi);
    float c2 = fminf(fmaxf(x2 * s, 0.0f), hi);
    float f0 = floorf(c0), f1 = floorf(c1), f2 = floorf(c2);
    cx = (int)f0; cy = (int)f1; cz = (int)f2;
    float xx = c0 - f0, yy = c1 - f1, zz = c2 - f2;
    wx[0] = 1.0f - xx; wx[1] = xx;
    wy[0] = 1.0f - yy; wy[1] = yy;
    wz[0] = 1.0f - zz; wz[1] = zz;
}

__device__ __forceinline__ void load_xyz(
    const float* __restrict__ x, const float4* __restrict__ xp, int i,
    float& x0, float& x1, float& x2)
{
    if (xp) {
        const float4 v = nt_load4(&xp[i]);
        x0 = v.x; x1 = v.y; x2 = v.z;
    } else {
        x0 = __builtin_nontemporal_load(&x[3 * i + 0]);
        x1 = __builtin_nontemporal_load(&x[3 * i + 1]);
        x2 = __builtin_nontemporal_load(&x[3 * i + 2]);
    }
}

// 8 gathers with sc0 (SE scope -> bypass vL1, serve from L2), one vmcnt.
// Early-clobber outputs so dest regs can't alias later address regs.
__device__ __forceinline__ void gather8_sc0(
    const float2* __restrict__ tab, const unsigned (&idx)[8], f2_t (&f)[8])
{
    const float2* p0 = tab + idx[0];
    const float2* p1 = tab + idx[1];
    const float2* p2 = tab + idx[2];
    const float2* p3 = tab + idx[3];
    const float2* p4 = tab + idx[4];
    const float2* p5 = tab + idx[5];
    const float2* p6 = tab + idx[6];
    const float2* p7 = tab + idx[7];
    asm volatile(
        "global_load_dwordx2 %0, %8, off sc0\n\t"
        "global_load_dwordx2 %1, %9, off sc0\n\t"
        "global_load_dwordx2 %2, %10, off sc0\n\t"
        "global_load_dwordx2 %3, %11, off sc0\n\t"
        "global_load_dwordx2 %4, %12, off sc0\n\t"
        "global_load_dwordx2 %5, %13, off sc0\n\t"
        "global_load_dwordx2 %6, %14, off sc0\n\t"
        "global_load_dwordx2 %7, %15, off sc0\n\t"
        "s_waitcnt vmcnt(0)"
        : "=&v"(f[0]), "=&v"(f[1]), "=&v"(f[2]), "=&v"(f[3]),
          "=&v"(f[4]), "=&v"(f[5]), "=&v"(f[6]), "=&v"(f[7])
        : "v"(p0), "v"(p1), "v"(p2), "v"(p3),
          "v"(p4), "v"(p5), "v"(p6), "v"(p7));
}

// ======================= optimized path =======================

struct DenseP {
    int res[6];
    int res2[6];
    float scale[6];
    float hi[6];
    long long packoff[4];   // float4-index offsets, levels 1..3
    long long nent[6];      // res^3
};

// Pack dense levels 1..3 into x-paired float4; optionally pack x into float4.
__global__ __launch_bounds__(256) void repack_kernel(
    const float* __restrict__ x,
    const float* __restrict__ tables,
    float4* __restrict__ pack,
    float4* __restrict__ xp,
    DenseP P)
{
    const long long stride = (long long)gridDim.x * 256;
    const long long tid = (long long)blockIdx.x * 256 + threadIdx.x;
    for (int l = 1; l <= 3; ++l) {
        const float2* tab = (const float2*)(tables + (size_t)l * MAX_ENTRY * 2);
        float4* dst = pack + P.packoff[l];
        const long long n = P.nent[l];
        for (long long k = tid; k < n; k += stride) {
            const float2 a = tab[k];
            const float2 b = tab[k + 1];   // within the level's MAX_ENTRY row
            nt_store4(make_float4(a.x, a.y, b.x, b.y), &dst[k]);
        }
    }
    if (xp) {
        for (long long i = tid; i < NPTS; i += stride) {
            xp[i] = make_float4(x[3 * i + 0], x[3 * i + 1], x[3 * i + 2], 0.0f);
        }
    }
}

// Dense levels 0..4. L0 in LDS; L1..3 packed float4; L4 adjacent-pair float2.
__global__ __launch_bounds__(256) void dense_kernel(
    const float* __restrict__ x,
    const float4* __restrict__ xp,
    const float* __restrict__ tables,
    const float4* __restrict__ pack,
    float2* __restrict__ feat,
    DenseP P)
{
    __shared__ float2 lds0[4096];
    {
        const float2* tab0 = (const float2*)tables;
        for (int j = threadIdx.x; j < 4096; j += 256) lds0[j] = tab0[j];
    }
    __syncthreads();

    const int i = blockIdx.x * 256 + threadIdx.x;
    if (i >= NPTS) return;

    float x0, x1, x2;
    load_xyz(x, xp, i, x0, x1, x2);

    // ---- level 0 from LDS ----
    {
        int cx, cy, cz;
        float wx[2], wy[2], wz[2];
        corner_setup(x0, x1, x2, P.scale[0], P.hi[0], cx, cy, cz, wx, wy, wz);
        const int res = P.res[0], res2 = P.res2[0];
        const int base = cx + cy * res + cz * res2;
        float a0 = 0.0f, a1 = 0.0f;
#pragma unroll
        for (int k = 0; k < 8; ++k) {
            const int idx = base + OX[k] + OY[k] * res + OZ[k] * res2;
            const float2 f = lds0[idx];
            const float w = wx[k & 1] * wy[(k >> 1) & 1] * wz[k >> 2];
            a0 += w * f.x; a1 += w * f.y;
        }
        nt_store2(make_float2(a0, a1), &feat[i]);
    }

    // ---- levels 1..3 from packed float4 ----
#pragma unroll
    for (int l = 1; l <= 3; ++l) {
        int cx, cy, cz;
        float wx[2], wy[2], wz[2];
        corner_setup(x0, x1, x2, P.scale[l], P.hi[l], cx, cy, cz, wx, wy, wz);
        const int res = P.res[l], res2 = P.res2[l];
        const int base = cx + cy * res + cz * res2;
        const float4* pk = pack + P.packoff[l];

        float a0 = 0.0f, a1 = 0.0f;
#pragma unroll
        for (int j = 0; j < 4; ++j) {
            const int idx = base + (j & 1) * res + (j >> 1) * res2;
            const float4 f = pk[idx];
            const float w0 = wx[j & 1] * wy[j >> 1] * wz[0];
            const float w1 = wx[j >> 1] * wy[j & 1] * wz[1];
            a0 += w0 * f.x + w1 * f.z;
            a1 += w0 * f.y + w1 * f.w;
        }
        nt_store2(make_float2(a0, a1), &feat[(size_t)l * NPTS + i]);
    }

    // ---- level 4 unpacked, adjacent-pair float2 ----
    {
        const int l = 4;
        int cx, cy, cz;
        float wx[2], wy[2], wz[2];
        corner_setup(x0, x1, x2, P.scale[l], P.hi[l], cx, cy, cz, wx, wy, wz);
        const int res = P.res[l], res2 = P.res2[l];
        const int base = cx + cy * res + cz * res2;
        const float2* tab = (const float2*)tables + (size_t)l * MAX_ENTRY;

        float a0 = 0.0f, a1 = 0.0f;
#pragma unroll
        for (int j = 0; j < 4; ++j) {
            const int idx = base + (j & 1) * res + (j >> 1) * res2;
            const float2 flo = tab[idx];
            const float2 fhi = tab[idx + 1];
            const float w0 = wx[j & 1] * wy[j >> 1] * wz[0];
            const float w1 = wx[j >> 1] * wy[j & 1] * wz[1];
            a0 += w0 * flo.x + w1 * fhi.x;
            a1 += w0 * flo.y + w1 * fhi.y;
        }
        nt_store2(make_float2(a0, a1), &feat[(size_t)l * NPTS + i]);
    }
}

// Level 5 (res=80, 4.1 MB table ~ L2): own pass, adjacent-pair float2, 2 pts/thread.
__global__ __launch_bounds__(256) void dense5_kernel(
    const float* __restrict__ x,
    const float4* __restrict__ xp,
    const float2* __restrict__ tab,
    float2* __restrict__ featl,
    int res, int res2, float scale, float hi)
{
    const int t = blockIdx.x * 256 + threadIdx.x;
#pragma unroll
    for (int h = 0; h < 2; ++h) {
        const int i = t + h * (NPTS / 2);
        float x0, x1, x2;
        load_xyz(x, xp, i, x0, x1, x2);

        int cx, cy, cz;
        float wx[2], wy[2], wz[2];
        corner_setup(x0, x1, x2, scale, hi, cx, cy, cz, wx, wy, wz);
        const int base = cx + cy * res + cz * res2;

        float a0 = 0.0f, a1 = 0.0f;
#pragma unroll
        for (int j = 0; j < 4; ++j) {
            const int idx = base + (j & 1) * res + (j >> 1) * res2;
            const float2 flo = tab[idx];
            const float2 fhi = tab[idx + 1];
            const float w0 = wx[j & 1] * wy[j >> 1] * wz[0];
            const float w1 = wx[j >> 1] * wy[j & 1] * wz[1];
            a0 += w0 * flo.x + w1 * fhi.x;
            a1 += w0 * flo.y + w1 * fhi.y;
        }
        nt_store2(make_float2(a0, a1), &featl[i]);
    }
}

// One hashed level per launch; 2 points/thread; sc0 (L1-bypass) gathers.
__global__ __launch_bounds__(256) void hash_kernel(
    const float* __restrict__ x,
    const float4* __restrict__ xp,
    const float2* __restrict__ tab,
    float2* __restrict__ featl,
    float scale, float hi)
{
    const int t = blockIdx.x * 256 + threadIdx.x;   // 0 .. NPTS/2-1
    const unsigned P0 = 3367900313u, P1 = 2654435761u, P2 = 805459861u;

#pragma unroll
    for (int h = 0; h < 2; ++h) {
        const int i = t + h * (NPTS / 2);
        float x0, x1, x2;
        load_xyz(x, xp, i, x0, x1, x2);

        int cx, cy, cz;
        float wx[2], wy[2], wz[2];
        corner_setup(x0, x1, x2, scale, hi, cx, cy, cz, wx, wy, wz);

        unsigned hx[2], hy[2], hz[2];
        hx[0] = (unsigned)cx * P0; hx[1] = hx[0] + P0;
        hy[0] = (unsigned)cy * P1; hy[1] = hy[0] + P1;
        hz[0] = (unsigned)cz * P2; hz[1] = hz[0] + P2;

        unsigned idx[8];
#pragma unroll
        for (int k = 0; k < 8; ++k) {
            idx[k] = (hx[OX[k]] ^ hy[OY[k]] ^ hz[OZ[k]]) & (MAX_ENTRY - 1);
        }

        f2_t f[8];
        gather8_sc0(tab, idx, f);

        float a0 = 0.0f, a1 = 0.0f;
#pragma unroll
        for (int k = 0; k < 8; ++k) {
            const float w = wx[k & 1] * wy[(k >> 1) & 1] * wz[k >> 2];
            a0 += w * f[k].x;
            a1 += w * f[k].y;
        }
        nt_store2(make_float2(a0, a1), &featl[i]);
    }
}

// feat[16][NPTS] (float2) -> out[NPTS][32] floats, coalesced float4 writes.
__global__ __launch_bounds__(256) void assemble_kernel(
    const float2* __restrict__ feat, float4* __restrict__ out)
{
    const size_t tid = (size_t)blockIdx.x * 256 + threadIdx.x;  // 0 .. 8M-1
    const int    c   = (int)(tid & 7);
    const size_t p   = tid >> 3;
    const float2 a = nt_load2(&feat[(size_t)(2 * c) * NPTS + p]);
    const float2 b = nt_load2(&feat[(size_t)(2 * c + 1) * NPTS + p]);
    nt_store4(make_float4(a.x, a.y, b.x, b.y), &out[tid]);
}

// ======================= fallback path (round-2, known-good) =======================

struct DenseParams {
    int   res[6];
    int   res2[6];
    float scale[6];
    float hi[6];
    long long tab_off[6];
};

__device__ __forceinline__ float2 hash_point_fb(
    float x0, float x1, float x2, const float2* __restrict__ tab,
    float scale, float hi)
{
    int cx, cy, cz;
    float wx[2], wy[2], wz[2];
    corner_setup(x0, x1, x2, scale, hi, cx, cy, cz, wx, wy, wz);
    const unsigned P0 = 3367900313u, P1 = 2654435761u, P2 = 805459861u;
    unsigned hx[2], hy[2], hz[2];
    hx[0] = (unsigned)cx * P0; hx[1] = hx[0] + P0;
    hy[0] = (unsigned)cy * P1; hy[1] = hy[0] + P1;
    hz[0] = (unsigned)cz * P2; hz[1] = hz[0] + P2;
    float a0 = 0.0f, a1 = 0.0f;
#pragma unroll
    for (int k = 0; k < 8; ++k) {
        const unsigned idx = (hx[OX[k]] ^ hy[OY[k]] ^ hz[OZ[k]]) & (MAX_ENTRY - 1);
        const float2 f = tab[idx];
        const float w = wx[k & 1] * wy[(k >> 1) & 1] * wz[k >> 2];
        a0 += w * f.x; a1 += w * f.y;
    }
    return make_float2(a0, a1);
}

__global__ __launch_bounds__(256) void dense6_kernel(
    const float* __restrict__ x,
    const float* __restrict__ tables,
    float* __restrict__ out,
    DenseParams P)
{
    const int i = blockIdx.x * 256 + threadIdx.x;
    if (i >= NPTS) return;
    const float x0 = x[3 * i + 0];
    const float x1 = x[3 * i + 1];
    const float x2 = x[3 * i + 2];
    float o[12];
#pragma unroll
    for (int l = 0; l < 6; ++l) {
        int cx, cy, cz;
        float wx[2], wy[2], wz[2];
        corner_setup(x0, x1, x2, P.scale[l], P.hi[l], cx, cy, cz, wx, wy, wz);
        const float2* tab = (const float2*)(tables + P.tab_off[l]);
        const int res  = P.res[l];
        const int res2 = P.res2[l];
        const int base = cx + cy * res + cz * res2;
        float a0 = 0.0f, a1 = 0.0f;
#pragma unroll
        for (int k = 0; k < 8; ++k) {
            const int idx = base + OX[k] + OY[k] * res + OZ[k] * res2;
            const float2 f = tab[idx];
            const float w = wx[k & 1] * wy[(k >> 1) & 1] * wz[k >> 2];
            a0 += w * f.x; a1 += w * f.y;
        }
        o[2 * l + 0] = a0; o[2 * l + 1] = a1;
    }
    float4* op = (float4*)(out + (size_t)i * 32);
    op[0] = ((float4*)o)[0];
    op[1] = ((float4*)o)[1];
    op[2] = ((float4*)o)[2];
}

__global__ __launch_bounds__(256) void hash_level_kernel(
    const float* __restrict__ x,
    const float* __restrict__ tables,
    float* __restrict__ out,
    int level, float scale, float hi)
{
    const int i = blockIdx.x * 256 + threadIdx.x;
    if (i >= NPTS) return;
    const float2* tab = (const float2*)tables + (size_t)level * MAX_ENTRY;
    const float2 r = hash_point_fb(x[3 * i], x[3 * i + 1], x[3 * i + 2], tab, scale, hi);
    *(float2*)(out + (size_t)i * 32 + 2 * level) = r;
}

__global__ __launch_bounds__(256) void generic_level_kernel(
    const float* __restrict__ x,
    const float* __restrict__ tables,
    float* __restrict__ out,
    int level, int res, int res2, int use_hash, float scale, float hi)
{
    const int i = blockIdx.x * 256 + threadIdx.x;
    if (i >= NPTS) return;
    const float x0 = x[3 * i + 0];
    const float x1 = x[3 * i + 1];
    const float x2 = x[3 * i + 2];
    int cx, cy, cz;
    float wx[2], wy[2], wz[2];
    corner_setup(x0, x1, x2, scale, hi, cx, cy, cz, wx, wy, wz);
    const float2* tab = (const float2*)tables + (size_t)level * MAX_ENTRY;
    float a0 = 0.0f, a1 = 0.0f;
    if (use_hash) {
        const unsigned P0 = 3367900313u, P1 = 2654435761u, P2 = 805459861u;
        unsigned hx[2], hy[2], hz[2];
        hx[0] = (unsigned)cx * P0; hx[1] = hx[0] + P0;
        hy[0] = (unsigned)cy * P1; hy[1] = hy[0] + P1;
        hz[0] = (unsigned)cz * P2; hz[1] = hz[0] + P2;
#pragma unroll
        for (int k = 0; k < 8; ++k) {
            const unsigned idx = (hx[OX[k]] ^ hy[OY[k]] ^ hz[OZ[k]]) & (MAX_ENTRY - 1);
            const float2 f = tab[idx];
            const float w = wx[k & 1] * wy[(k >> 1) & 1] * wz[k >> 2];
            a0 += w * f.x; a1 += w * f.y;
        }
    } else {
        const int base = cx + cy * res + cz * res2;
#pragma unroll
        for (int k = 0; k < 8; ++k) {
            const int idx = base + OX[k] + OY[k] * res + OZ[k] * res2;
            const float2 f = tab[idx];
            const float w = wx[k & 1] * wy[(k >> 1) & 1] * wz[k >> 2];
            a0 += w * f.x; a1 += w * f.y;
        }
    }
    *(float2*)(out + (size_t)i * 32 + 2 * level) = make_float2(a0, a1);
}

// ======================= launch =======================

extern "C" void kernel_launch(void* const* d_in, const int* in_sizes, int n_in,
                              void* d_out, int out_size, void* d_ws, size_t ws_size,
                              hipStream_t stream)
{
    const float* x      = (const float*)d_in[0];
    const float* tables = (const float*)d_in[1];
    float* out          = (float*)d_out;

    // Reproduce numpy's resolution computation bit-for-bit (same libm).
    int   res[NLVL], res2[NLVL], use_hash[NLVL];
    float scale[NLVL], hi[NLVL];
    const double b = exp((log(2048.0) - log(16.0)) / 15.0);
    for (int l = 0; l < NLVL; ++l) {
        const int r = (int)floor(16.0 * pow(b, (double)l));
        res[l]  = r;
        res2[l] = r * r;
        const long long t3 = (long long)r * r * r;
        use_hash[l] = (t3 >= (long long)MAX_ENTRY) ? 1 : 0;
        scale[l] = (float)(r - 1);
        hi[l]    = (float)((double)r - 1.0001);
    }

    const int block = 256;
    const int grid  = (NPTS + block - 1) / block;

    bool expected = true;
    for (int l = 0; l < 6; ++l)    expected = expected && !use_hash[l];
    for (int l = 6; l < NLVL; ++l) expected = expected && use_hash[l];

    // Workspace layout: pack (levels 1..3) | feat | [optional xp]
    long long packoff[4] = {0, 0, 0, 0};
    long long nent[6];
    long long packTot = 0;
    if (expected) {
        for (int l = 0; l < 6; ++l) nent[l] = (long long)res[l] * res[l] * res[l];
        for (int l = 1; l <= 3; ++l) { packoff[l] = packTot; packTot += nent[l]; }
    }
    const size_t packBytes = (size_t)packTot * 16;
    const size_t featOff   = (packBytes + 255) & ~(size_t)255;
    const size_t featBytes = (size_t)NLVL * NPTS * sizeof(float2);
    const size_t xpOff     = (featOff + featBytes + 255) & ~(size_t)255;
    const size_t need      = featOff + featBytes;
    const size_t need_xp   = xpOff + (size_t)NPTS * sizeof(float4);

    if (expected && ws_size >= need) {
        float4* pack = (float4*)d_ws;
        float2* feat = (float2*)((char*)d_ws + featOff);
        float4* xp   = (ws_size >= need_xp) ? (float4*)((char*)d_ws + xpOff) : nullptr;

        DenseP P;
        for (int l = 0; l < 6; ++l) {
            P.res[l] = res[l]; P.res2[l] = res2[l];
            P.scale[l] = scale[l]; P.hi[l] = hi[l];
            P.nent[l] = nent[l];
        }
        for (int l = 1; l <= 3; ++l) P.packoff[l] = packoff[l];
        P.packoff[0] = 0;

        repack_kernel<<<1024, block, 0, stream>>>(x, tables, pack, xp, P);
        dense_kernel<<<grid, block, 0, stream>>>(x, xp, tables, pack, feat, P);
        dense5_kernel<<<NPTS / 2 / block, block, 0, stream>>>(
            x, xp, (const float2*)tables + (size_t)5 * MAX_ENTRY,
            feat + (size_t)5 * NPTS, res[5], res2[5], scale[5], hi[5]);
        for (int l = 6; l < NLVL; ++l) {
            const float2* tab = (const float2*)tables + (size_t)l * MAX_ENTRY;
            hash_kernel<<<NPTS / 2 / block, block, 0, stream>>>(
                x, xp, tab, feat + (size_t)l * NPTS, scale[l], hi[l]);
        }
        assemble_kernel<<<(NPTS * 8) / block, block, 0, stream>>>(feat, (float4*)out);
    } else if (expected) {
        DenseParams P;
        for (int l = 0; l < 6; ++l) {
            P.res[l] = res[l]; P.res2[l] = res2[l];
            P.scale[l] = scale[l]; P.hi[l] = hi[l];
            P.tab_off[l] = (long long)l * MAX_ENTRY * 2;
        }
        dense6_kernel<<<grid, block, 0, stream>>>(x, tables, out, P);
        for (int l = 6; l < NLVL; ++l) {
            hash_level_kernel<<<grid, block, 0, stream>>>(x, tables, out, l, scale[l], hi[l]);
        }
    } else {
        for (int l = 0; l < NLVL; ++l) {
            generic_level_kernel<<<grid, block, 0, stream>>>(
                x, tables, out, l, res[l], res2[l], use_hash[l], scale[l], hi[l]);
        }
    }
}